// Round 21
// baseline (117.993 us; speedup 1.0000x reference)
//
#include <hip/hip_runtime.h>
#include <math.h>

#define BB 4096        // batch size
#define DD 512         // repr dim
#define KTOP 9         // K+1
#define MARGIN_F 0.2f
#define NT 32          // 4096/128
#define NTRI (NT * (NT + 1) / 2)   // 528 upper-triangle 128x128 blocks

typedef __attribute__((ext_vector_type(8))) short short8;
typedef __attribute__((ext_vector_type(4))) float f32x4;
typedef unsigned long long u64;

__device__ unsigned short g_Rhi[(size_t)BB * DD];
__device__ u64 g_cmask[64 * 64];   // [class][lane] bit e -> label[j(lane,e)]==class

// ---- bf16 helper (RNE) ----
__device__ __forceinline__ unsigned short f2bf(float x) {
  unsigned u = __float_as_uint(x);
  u += 0x7fffu + ((u >> 16) & 1u);
  return (unsigned short)(u >> 16);
}

// ---- 16-bit ord: monotone map of f32, truncated; dequant mid-bucket ----
__device__ __forceinline__ float ord16val(unsigned o16) {
  unsigned e = (o16 << 16) | 0x8000u;
  unsigned s = (e & 0x80000000u) ? (e ^ 0x80000000u) : ~e;
  return __uint_as_float(s);
}

// ---- DPP wave reductions ----
__device__ __forceinline__ unsigned wavemax32_dpp(unsigned c) {
#define MSTEP(CTRL, RM)                                                        \
  {                                                                            \
    unsigned o = (unsigned)__builtin_amdgcn_update_dpp(0, (int)c, CTRL, RM, 0xf, false); \
    if (o > c) c = o;                                                          \
  }
  MSTEP(0xB1, 0xf) MSTEP(0x4E, 0xf) MSTEP(0x141, 0xf) MSTEP(0x140, 0xf)
  MSTEP(0x142, 0xa) MSTEP(0x143, 0xc)
#undef MSTEP
  return (unsigned)__builtin_amdgcn_readlane((int)c, 63);
}

__device__ __forceinline__ int wavesum_dpp(int c) {
#define SSTEP(CTRL, RM)                                                        \
  c += __builtin_amdgcn_update_dpp(0, c, CTRL, RM, 0xf, false);
  SSTEP(0xB1, 0xf) SSTEP(0x4E, 0xf) SSTEP(0x141, 0xf) SSTEP(0x140, 0xf)
  SSTEP(0x142, 0xa) SSTEP(0x143, 0xc)
#undef SSTEP
  return __builtin_amdgcn_readlane(c, 63);
}

// ---------------- K0: split R -> bf16 hi + row sqnorms ----------------
__global__ __launch_bounds__(64) void splitsq(const float* __restrict__ R,
                                              float* __restrict__ sq) {
  const int row = blockIdx.x, lane = threadIdx.x;
  const float4* r4 = (const float4*)(R + (size_t)row * DD);
  float4 a = r4[lane], b = r4[lane + 64];
  float xs[8] = {a.x, a.y, a.z, a.w, b.x, b.y, b.z, b.w};
  unsigned short hs[8];
  float s = 0.f;
  #pragma unroll
  for (int q = 0; q < 8; ++q) {
    float x = xs[q];
    s += x * x;
    hs[q] = f2bf(x);
  }
  const size_t base = (size_t)row * DD;
  *(ushort4*)&g_Rhi[base + lane * 4]       = *(ushort4*)&hs[0];
  *(ushort4*)&g_Rhi[base + 256 + lane * 4] = *(ushort4*)&hs[4];
  #pragma unroll
  for (int off = 32; off; off >>= 1) s += __shfl_down(s, off);
  if (lane == 0) sq[row] = s;
}

// ---------------- K0b: per-class match bitmasks ----------------
// bit e of g_cmask[c][lane] <-> j = 512*(e>>3) + 8*lane + (e&7)  (u16-row layout)
__global__ __launch_bounds__(64) void buildmask(const int* __restrict__ labels) {
  __shared__ int slab[BB];
  const int c = blockIdx.x, lane = threadIdx.x;
  for (int i = lane; i < BB / 4; i += 64) ((int4*)slab)[i] = ((const int4*)labels)[i];
  __syncthreads();
  u64 m = 0;
  #pragma unroll
  for (int e = 0; e < 64; ++e) {
    int j = 512 * (e >> 3) + 8 * lane + (e & 7);
    m |= (u64)(slab[j] == c) << e;
  }
  g_cmask[c * 64 + lane] = m;
}

// ---------------- K1: 128x128 MFMA GEMM, BK=64 dbuf, reg-staging (R18 best-known) ----------------
__global__ __launch_bounds__(256, 2) void simgemm_rs2(const int* __restrict__ labels,
                                                      const float* __restrict__ sq,
                                                      unsigned short* __restrict__ simq) {
  const int x = blockIdx.x & 7;      // XCD (round-robin dispatch)
  int c = blockIdx.x >> 3;           // 0..65 within XCD
  int bi = 0, bj = 0;
  #pragma unroll
  for (int q = 0; q < 4; ++q) {
    const int bjq = (q < 2) ? (2 * x + q) : (28 - 2 * x + q);   // {2x,2x+1,30-2x,31-2x}
    const int n = bjq + 1;
    if (c >= 0 && c < n) { bj = bjq; bi = c; }
    c -= n;
  }
  const int i0 = bi * 128, j0 = bj * 128;

  __shared__ __align__(16) unsigned char smembytes[65536];
  unsigned short (*kbuf)[2][8192] = (unsigned short (*)[2][8192])smembytes;

  const int tid = threadIdx.x;
  const int wid = tid >> 6, lane = tid & 63;
  const int wr = wid >> 1, wc = wid & 1;
  const int lrow = lane & 15, kblk = lane >> 4;

  const int sr = lane & 15;
  const int sc = (lane >> 4) * 8;
  const int r0 = (2 * wid + 0) * 16 + sr;
  const int r1 = (2 * wid + 1) * 16 + sr;
  const unsigned short* gA0 = &g_Rhi[(size_t)(i0 + r0) * DD + sc];
  const unsigned short* gA1 = &g_Rhi[(size_t)(i0 + r1) * DD + sc];
  const unsigned short* gB0 = &g_Rhi[(size_t)(j0 + r0) * DD + sc];
  const unsigned short* gB1 = &g_Rhi[(size_t)(j0 + r1) * DD + sc];

  f32x4 acc[4][4] = {};
  uint4 vA00, vA01, vA10, vA11, vB00, vB01, vB10, vB11;

#define STAGE_LOAD(K0)                                                         \
  vA00 = *(const uint4*)(gA0 + (K0));      vB00 = *(const uint4*)(gB0 + (K0)); \
  vA01 = *(const uint4*)(gA0 + (K0) + 32); vB01 = *(const uint4*)(gB0 + (K0) + 32); \
  vA10 = *(const uint4*)(gA1 + (K0));      vB10 = *(const uint4*)(gB1 + (K0)); \
  vA11 = *(const uint4*)(gA1 + (K0) + 32); vB11 = *(const uint4*)(gB1 + (K0) + 32);

#define STAGE_WRITE(BUF)                                                       \
  {                                                                            \
    const int c0 = (2 * wid + 0) * 1024 + lane * 8;                            \
    const int c1 = (2 * wid + 1) * 1024 + lane * 8;                            \
    *(uint4*)&kbuf[BUF][0][c0]       = vA00; *(uint4*)&kbuf[BUF][1][c0]       = vB00; \
    *(uint4*)&kbuf[BUF][0][c0 + 512] = vA01; *(uint4*)&kbuf[BUF][1][c0 + 512] = vB01; \
    *(uint4*)&kbuf[BUF][0][c1]       = vA10; *(uint4*)&kbuf[BUF][1][c1]       = vB10; \
    *(uint4*)&kbuf[BUF][0][c1 + 512] = vA11; *(uint4*)&kbuf[BUF][1][c1 + 512] = vB11; \
  }

  STAGE_LOAD(0);
  STAGE_WRITE(0);
  STAGE_LOAD(64);
  __syncthreads();

  for (int step = 0; step < 8; ++step) {
    const int cur = step & 1;

    #pragma unroll
    for (int kk = 0; kk < 2; ++kk) {
      short8 a[4], b[4];
      #pragma unroll
      for (int m = 0; m < 4; ++m)
        a[m] = *(const short8*)&kbuf[cur][0][(wr * 4 + m) * 1024 + kk * 512 + lane * 8];
      #pragma unroll
      for (int n = 0; n < 4; ++n)
        b[n] = *(const short8*)&kbuf[cur][1][(wc * 4 + n) * 1024 + kk * 512 + lane * 8];
      #pragma unroll
      for (int m = 0; m < 4; ++m) {
        #pragma unroll
        for (int n = 0; n < 4; ++n) {
          acc[m][n] = __builtin_amdgcn_mfma_f32_16x16x32_bf16(a[m], b[n], acc[m][n], 0, 0, 0);
        }
      }
    }

    if (step < 7) {
      STAGE_WRITE(cur ^ 1);
      if (step < 6) { STAGE_LOAD((step + 2) * 64); }
      __syncthreads();
    }
  }
#undef STAGE_LOAD
#undef STAGE_WRITE

  __syncthreads();
  unsigned short (*T)[132] = (unsigned short (*)[132])smembytes;   // 33792 B
  float* sqi = (float*)(smembytes + 33792);
  float* sqj = (float*)(smembytes + 34304);
  int* labi  = (int*)(smembytes + 34816);
  int* labj  = (int*)(smembytes + 35328);
  if (tid < 128) { sqi[tid] = sq[i0 + tid]; labi[tid] = labels[i0 + tid]; }
  else { int t2 = tid - 128; sqj[t2] = sq[j0 + t2]; labj[t2] = labels[j0 + t2]; }
  __syncthreads();

  #pragma unroll
  for (int m = 0; m < 4; ++m) {
    const int rbase = wr * 64 + m * 16 + kblk * 4;
    #pragma unroll
    for (int n = 0; n < 4; ++n) {
      const int ccol = wc * 64 + n * 16 + lrow;
      const float sqc = sqj[ccol];
      const int lc_ = labj[ccol];
      #pragma unroll
      for (int reg = 0; reg < 4; ++reg) {
        const int r = rbase + reg;
        float res = sqi[r] - 2.0f * acc[m][n][reg] + sqc;
        float dd = (res <= 0.f) ? 0.f : sqrtf(res);
        float sv = -dd + ((labi[r] != lc_) ? MARGIN_F : 0.f);
        unsigned su = __float_as_uint(sv);
        unsigned ord = su ^ ((unsigned)((int)su >> 31) | 0x80000000u);
        T[r][ccol] = (unsigned short)(ord >> 16);
      }
    }
  }
  __syncthreads();

  const int srow0 = tid >> 4, scol0 = (tid & 15) * 8;
  #pragma unroll
  for (int p = 0; p < 8; ++p) {
    const int r = p * 16 + srow0;
    short8 w = *(const short8*)&T[r][scol0];
    *(short8*)&simq[(size_t)(i0 + r) * BB + j0 + scol0] = w;
  }
  if (bi != bj) {
    #pragma unroll
    for (int p = 0; p < 8; ++p) {
      const int col = p * 16 + srow0;
      unsigned short tmp[8];
      #pragma unroll
      for (int t = 0; t < 8; ++t) tmp[t] = T[scol0 + t][col];
      *(short8*)&simq[(size_t)(j0 + col) * BB + i0 + scol0] = *(short8*)tmp;
    }
  }
}

// ---------------- K2: rank processing, 4 rows/wave, next-row prefetch pipeline ----------------
// Element e (0..63) of lane: j = 512*(e>>3) + 8*lane + (e&7).
// key = ord16<<13 | (4095-j)<<1 | match. While row r's pops/counts run
// (~4k cyc), row r+1's 8 uint4 loads + label + cmask are in flight.
#define TOP2UPD(k, a, b) {                                                     \
  unsigned _mx = ((k) > (a)) ? (k) : (a);                                      \
  unsigned _mn = ((k) > (a)) ? (a) : (k);                                      \
  (a) = _mx;                                                                   \
  (b) = (_mn > (b)) ? _mn : (b); }

#define KB(S, W)                                                               \
  {                                                                            \
    const unsigned base_s = lbase2 - (unsigned)(1024 * (S));                   \
    k[(S)*8+0] = (((W).x & 0xffffu) << 13) | (base_s -  0u + (unsigned)((mask >> ((S)*8+0)) & 1ull)); \
    k[(S)*8+1] = (((W).x >> 16)     << 13) | (base_s -  2u + (unsigned)((mask >> ((S)*8+1)) & 1ull)); \
    k[(S)*8+2] = (((W).y & 0xffffu) << 13) | (base_s -  4u + (unsigned)((mask >> ((S)*8+2)) & 1ull)); \
    k[(S)*8+3] = (((W).y >> 16)     << 13) | (base_s -  6u + (unsigned)((mask >> ((S)*8+3)) & 1ull)); \
    k[(S)*8+4] = (((W).z & 0xffffu) << 13) | (base_s -  8u + (unsigned)((mask >> ((S)*8+4)) & 1ull)); \
    k[(S)*8+5] = (((W).z >> 16)     << 13) | (base_s - 10u + (unsigned)((mask >> ((S)*8+5)) & 1ull)); \
    k[(S)*8+6] = (((W).w & 0xffffu) << 13) | (base_s - 12u + (unsigned)((mask >> ((S)*8+6)) & 1ull)); \
    k[(S)*8+7] = (((W).w >> 16)     << 13) | (base_s - 14u + (unsigned)((mask >> ((S)*8+7)) & 1ull)); \
  }

__global__ __launch_bounds__(256, 1) void rowproc8(const unsigned short* __restrict__ simq,
                                                   const int* __restrict__ labels,
                                                   float* __restrict__ partials) {
  const int tid = threadIdx.x;
  const int lane = tid & 63;
  const int row0 = blockIdx.x * 16 + (tid >> 6) * 4;
  const unsigned lbase2 = (unsigned)((4095 - 8 * lane) << 1);

  uint4 w0, w1, w2, w3, w4, w5, w6, w7;
  {
    const uint4* rp = (const uint4*)(simq + (size_t)row0 * BB);
    w0 = rp[lane];       w1 = rp[lane + 64];  w2 = rp[lane + 128]; w3 = rp[lane + 192];
    w4 = rp[lane + 256]; w5 = rp[lane + 320]; w6 = rp[lane + 384]; w7 = rp[lane + 448];
  }
  int myl = labels[row0];
  u64 mask = g_cmask[myl * 64 + lane];

  for (int rr = 0; rr < 4; ++rr) {
    const int row = row0 + rr;

    unsigned k[64];
    KB(0, w0) KB(1, w1) KB(2, w2) KB(3, w3)
    KB(4, w4) KB(5, w5) KB(6, w6) KB(7, w7)
    const int pos = wavesum_dpp(__popcll(mask));
    const int ks = min(pos, KTOP);

    // issue next-row loads NOW -- they land during the pop/count phases
    int nlab = 0;
    if (rr < 3) {
      const uint4* rp = (const uint4*)(simq + (size_t)(row + 1) * BB);
      w0 = rp[lane];       w1 = rp[lane + 64];  w2 = rp[lane + 128]; w3 = rp[lane + 192];
      w4 = rp[lane + 256]; w5 = rp[lane + 320]; w6 = rp[lane + 384]; w7 = rp[lane + 448];
      nlab = labels[row + 1];
    }

    unsigned h1 = 0, h2 = 0;
    #pragma unroll
    for (int e = 0; e < 64; ++e) TOP2UPD(k[e], h1, h2);

    unsigned kth = 0;
    float fp = 0.f; int fpn = 0;
    #pragma unroll
    for (int t = 0; t < KTOP; ++t) {
      if (t < ks) {
        unsigned g = wavemax32_dpp(h1);
        if (!(g & 1u)) { fp += ord16val(g >> 13) * (1.f / log2f((float)(t + 2)) + 1.f); fpn++; }
        if (t == ks - 1) kth = g;
        if (h1 == g) {
          h1 = h2; h2 = ~0u;
          if (h1 == ~0u) {
            h1 = 0; h2 = 0;
            #pragma unroll
            for (int e = 0; e < 64; ++e) {
              if (k[e] < g) TOP2UPD(k[e], h1, h2);
            }
          }
        }
      }
    }

    // dependent cmask prefetch: nlab has arrived by now; load flies under FN phase
    u64 nmask = 0;
    if (rr < 3) nmask = g_cmask[nlab * 64 + lane];

    float fn = 0.f;
    if (fpn > 0) {
      unsigned f1 = 0, f2 = 0;
      #pragma unroll
      for (int e = 0; e < 64; ++e) {
        if ((k[e] & 1u) && k[e] < kth) TOP2UPD(k[e], f1, f2);
      }
      unsigned ck[KTOP];
      int nc = 0;
      #pragma unroll
      for (int u = 0; u < KTOP; ++u) {
        ck[u] = ~0u;
        if (u < fpn) {
          unsigned g = wavemax32_dpp(f1);
          if (g != 0u) {
            ck[u] = g; nc = u + 1;
            if (f1 == g) {
              f1 = f2; f2 = ~0u;
              if (f1 == ~0u) {
                f1 = 0; f2 = 0;
                #pragma unroll
                for (int e = 0; e < 64; ++e) {
                  if ((k[e] & 1u) && k[e] < g) TOP2UPD(k[e], f1, f2);
                }
              }
            }
          }
        }
      }
      if (nc > 0) {
        int cnt[KTOP];
        #pragma unroll
        for (int u = 0; u < KTOP; ++u) cnt[u] = 0;
        #pragma unroll
        for (int e = 0; e < 64; ++e) {
          #pragma unroll
          for (int u = 0; u < KTOP; ++u) cnt[u] += (k[e] > ck[u]) ? 1 : 0;
        }
        #pragma unroll
        for (int u = 0; u < KTOP; ++u) cnt[u] = wavesum_dpp(cnt[u]);
        #pragma unroll
        for (int u = 0; u < KTOP; ++u) {
          if (u < nc) {
            int rank = 1 + cnt[u];
            fn += ord16val(ck[u] >> 13) * (1.f / log2f((float)(rank + 1)) + 1.f);
          }
        }
      }
    }

    if (lane == 0) partials[row] = fp - fn;
    myl = nlab;
    mask = nmask;
  }
}

// ---------------- K3: deterministic final reduction ----------------
__global__ __launch_bounds__(256) void finalreduce(const float* __restrict__ partials,
                                                   float* __restrict__ out) {
  __shared__ float s[256];
  const int tid = threadIdx.x;
  float acc = 0.f;
  for (int j = tid; j < BB; j += 256) acc += partials[j];
  s[tid] = acc; __syncthreads();
  #pragma unroll
  for (int st = 128; st; st >>= 1) { if (tid < st) s[tid] += s[tid + st]; __syncthreads(); }
  if (tid == 0) out[0] = s[0];
}

extern "C" void kernel_launch(void* const* d_in, const int* in_sizes, int n_in,
                              void* d_out, int out_size, void* d_ws, size_t ws_size,
                              hipStream_t stream) {
  const float* R      = (const float*)d_in[0];
  const int*   labels = (const int*)d_in[1];
  float* out = (float*)d_out;

  unsigned short* simq = (unsigned short*)d_ws;                          // 32 MB
  float* sq            = (float*)((char*)d_ws + (size_t)BB * BB * 2);    // 16 KB
  float* partials      = sq + BB;                                        // 16 KB

  splitsq<<<BB, 64, 0, stream>>>(R, sq);
  buildmask<<<64, 64, 0, stream>>>(labels);
  simgemm_rs2<<<NTRI, 256, 0, stream>>>(labels, sq, simq);
  rowproc8<<<256, 256, 0, stream>>>(simq, labels, partials);
  finalreduce<<<1, 256, 0, stream>>>(partials, out);
}

// Round 22
// 93.060 us; speedup vs baseline: 1.2679x; 1.2679x over previous
//
#include <hip/hip_runtime.h>
#include <math.h>

#define BB 4096        // batch size
#define DD 512         // repr dim
#define KTOP 9         // K+1
#define MARGIN_F 0.2f
#define NT 32          // 4096/128
#define NTRI (NT * (NT + 1) / 2)   // 528 upper-triangle 128x128 blocks

typedef __attribute__((ext_vector_type(8))) short short8;
typedef __attribute__((ext_vector_type(4))) float f32x4;
typedef unsigned long long u64;

__device__ unsigned short g_Rhi[(size_t)BB * DD];
__device__ u64 g_cmask[64 * 64];   // [class][lane] bit e -> label[j(lane,e)]==class

// ---- bf16 helper (RNE) ----
__device__ __forceinline__ unsigned short f2bf(float x) {
  unsigned u = __float_as_uint(x);
  u += 0x7fffu + ((u >> 16) & 1u);
  return (unsigned short)(u >> 16);
}

// ---- 16-bit ord: monotone map of f32, truncated; dequant mid-bucket ----
__device__ __forceinline__ float ord16val(unsigned o16) {
  unsigned e = (o16 << 16) | 0x8000u;
  unsigned s = (e & 0x80000000u) ? (e ^ 0x80000000u) : ~e;
  return __uint_as_float(s);
}

// ---- DPP wave reductions ----
__device__ __forceinline__ unsigned wavemax32_dpp(unsigned c) {
#define MSTEP(CTRL, RM)                                                        \
  {                                                                            \
    unsigned o = (unsigned)__builtin_amdgcn_update_dpp(0, (int)c, CTRL, RM, 0xf, false); \
    if (o > c) c = o;                                                          \
  }
  MSTEP(0xB1, 0xf) MSTEP(0x4E, 0xf) MSTEP(0x141, 0xf) MSTEP(0x140, 0xf)
  MSTEP(0x142, 0xa) MSTEP(0x143, 0xc)
#undef MSTEP
  return (unsigned)__builtin_amdgcn_readlane((int)c, 63);
}

__device__ __forceinline__ int wavesum_dpp(int c) {
#define SSTEP(CTRL, RM)                                                        \
  c += __builtin_amdgcn_update_dpp(0, c, CTRL, RM, 0xf, false);
  SSTEP(0xB1, 0xf) SSTEP(0x4E, 0xf) SSTEP(0x141, 0xf) SSTEP(0x140, 0xf)
  SSTEP(0x142, 0xa) SSTEP(0x143, 0xc)
#undef SSTEP
  return __builtin_amdgcn_readlane(c, 63);
}

__device__ __forceinline__ unsigned u4c(const uint4& f, int q) {
  return q == 0 ? f.x : q == 1 ? f.y : q == 2 ? f.z : f.w;
}

// ---------------- K0: split R -> bf16 hi + row sqnorms ----------------
__global__ __launch_bounds__(64) void splitsq(const float* __restrict__ R,
                                              float* __restrict__ sq) {
  const int row = blockIdx.x, lane = threadIdx.x;
  const float4* r4 = (const float4*)(R + (size_t)row * DD);
  float4 a = r4[lane], b = r4[lane + 64];
  float xs[8] = {a.x, a.y, a.z, a.w, b.x, b.y, b.z, b.w};
  unsigned short hs[8];
  float s = 0.f;
  #pragma unroll
  for (int q = 0; q < 8; ++q) {
    float x = xs[q];
    s += x * x;
    hs[q] = f2bf(x);
  }
  const size_t base = (size_t)row * DD;
  *(ushort4*)&g_Rhi[base + lane * 4]       = *(ushort4*)&hs[0];
  *(ushort4*)&g_Rhi[base + 256 + lane * 4] = *(ushort4*)&hs[4];
  #pragma unroll
  for (int off = 32; off; off >>= 1) s += __shfl_down(s, off);
  if (lane == 0) sq[row] = s;
}

// ---------------- K0b: per-class match bitmasks ----------------
// bit e of g_cmask[c][lane] <-> j = 512*(e>>3) + 8*lane + (e&7)  (u16-row layout)
__global__ __launch_bounds__(64) void buildmask(const int* __restrict__ labels) {
  __shared__ int slab[BB];
  const int c = blockIdx.x, lane = threadIdx.x;
  for (int i = lane; i < BB / 4; i += 64) ((int4*)slab)[i] = ((const int4*)labels)[i];
  __syncthreads();
  u64 m = 0;
  #pragma unroll
  for (int e = 0; e < 64; ++e) {
    int j = 512 * (e >> 3) + 8 * lane + (e & 7);
    m |= (u64)(slab[j] == c) << e;
  }
  g_cmask[c * 64 + lane] = m;
}

// ---------------- K1: 128x128 MFMA GEMM, BK=64 dbuf, reg-staging (R18 best-known) ----------------
__global__ __launch_bounds__(256, 2) void simgemm_rs2(const int* __restrict__ labels,
                                                      const float* __restrict__ sq,
                                                      unsigned short* __restrict__ simq) {
  const int x = blockIdx.x & 7;      // XCD (round-robin dispatch)
  int c = blockIdx.x >> 3;           // 0..65 within XCD
  int bi = 0, bj = 0;
  #pragma unroll
  for (int q = 0; q < 4; ++q) {
    const int bjq = (q < 2) ? (2 * x + q) : (28 - 2 * x + q);   // {2x,2x+1,30-2x,31-2x}
    const int n = bjq + 1;
    if (c >= 0 && c < n) { bj = bjq; bi = c; }
    c -= n;
  }
  const int i0 = bi * 128, j0 = bj * 128;

  __shared__ __align__(16) unsigned char smembytes[65536];
  unsigned short (*kbuf)[2][8192] = (unsigned short (*)[2][8192])smembytes;

  const int tid = threadIdx.x;
  const int wid = tid >> 6, lane = tid & 63;
  const int wr = wid >> 1, wc = wid & 1;
  const int lrow = lane & 15, kblk = lane >> 4;

  const int sr = lane & 15;
  const int sc = (lane >> 4) * 8;
  const int r0 = (2 * wid + 0) * 16 + sr;
  const int r1 = (2 * wid + 1) * 16 + sr;
  const unsigned short* gA0 = &g_Rhi[(size_t)(i0 + r0) * DD + sc];
  const unsigned short* gA1 = &g_Rhi[(size_t)(i0 + r1) * DD + sc];
  const unsigned short* gB0 = &g_Rhi[(size_t)(j0 + r0) * DD + sc];
  const unsigned short* gB1 = &g_Rhi[(size_t)(j0 + r1) * DD + sc];

  f32x4 acc[4][4] = {};
  uint4 vA00, vA01, vA10, vA11, vB00, vB01, vB10, vB11;

#define STAGE_LOAD(K0)                                                         \
  vA00 = *(const uint4*)(gA0 + (K0));      vB00 = *(const uint4*)(gB0 + (K0)); \
  vA01 = *(const uint4*)(gA0 + (K0) + 32); vB01 = *(const uint4*)(gB0 + (K0) + 32); \
  vA10 = *(const uint4*)(gA1 + (K0));      vB10 = *(const uint4*)(gB1 + (K0)); \
  vA11 = *(const uint4*)(gA1 + (K0) + 32); vB11 = *(const uint4*)(gB1 + (K0) + 32);

#define STAGE_WRITE(BUF)                                                       \
  {                                                                            \
    const int c0 = (2 * wid + 0) * 1024 + lane * 8;                            \
    const int c1 = (2 * wid + 1) * 1024 + lane * 8;                            \
    *(uint4*)&kbuf[BUF][0][c0]       = vA00; *(uint4*)&kbuf[BUF][1][c0]       = vB00; \
    *(uint4*)&kbuf[BUF][0][c0 + 512] = vA01; *(uint4*)&kbuf[BUF][1][c0 + 512] = vB01; \
    *(uint4*)&kbuf[BUF][0][c1]       = vA10; *(uint4*)&kbuf[BUF][1][c1]       = vB10; \
    *(uint4*)&kbuf[BUF][0][c1 + 512] = vA11; *(uint4*)&kbuf[BUF][1][c1 + 512] = vB11; \
  }

  STAGE_LOAD(0);
  STAGE_WRITE(0);
  STAGE_LOAD(64);
  __syncthreads();

  for (int step = 0; step < 8; ++step) {
    const int cur = step & 1;

    #pragma unroll
    for (int kk = 0; kk < 2; ++kk) {
      short8 a[4], b[4];
      #pragma unroll
      for (int m = 0; m < 4; ++m)
        a[m] = *(const short8*)&kbuf[cur][0][(wr * 4 + m) * 1024 + kk * 512 + lane * 8];
      #pragma unroll
      for (int n = 0; n < 4; ++n)
        b[n] = *(const short8*)&kbuf[cur][1][(wc * 4 + n) * 1024 + kk * 512 + lane * 8];
      #pragma unroll
      for (int m = 0; m < 4; ++m) {
        #pragma unroll
        for (int n = 0; n < 4; ++n) {
          acc[m][n] = __builtin_amdgcn_mfma_f32_16x16x32_bf16(a[m], b[n], acc[m][n], 0, 0, 0);
        }
      }
    }

    if (step < 7) {
      STAGE_WRITE(cur ^ 1);
      if (step < 6) { STAGE_LOAD((step + 2) * 64); }
      __syncthreads();
    }
  }
#undef STAGE_LOAD
#undef STAGE_WRITE

  __syncthreads();
  unsigned short (*T)[132] = (unsigned short (*)[132])smembytes;   // 33792 B
  float* sqi = (float*)(smembytes + 33792);
  float* sqj = (float*)(smembytes + 34304);
  int* labi  = (int*)(smembytes + 34816);
  int* labj  = (int*)(smembytes + 35328);
  if (tid < 128) { sqi[tid] = sq[i0 + tid]; labi[tid] = labels[i0 + tid]; }
  else { int t2 = tid - 128; sqj[t2] = sq[j0 + t2]; labj[t2] = labels[j0 + t2]; }
  __syncthreads();

  #pragma unroll
  for (int m = 0; m < 4; ++m) {
    const int rbase = wr * 64 + m * 16 + kblk * 4;
    #pragma unroll
    for (int n = 0; n < 4; ++n) {
      const int ccol = wc * 64 + n * 16 + lrow;
      const float sqc = sqj[ccol];
      const int lc_ = labj[ccol];
      #pragma unroll
      for (int reg = 0; reg < 4; ++reg) {
        const int r = rbase + reg;
        float res = sqi[r] - 2.0f * acc[m][n][reg] + sqc;
        float dd = (res <= 0.f) ? 0.f : sqrtf(res);
        float sv = -dd + ((labi[r] != lc_) ? MARGIN_F : 0.f);
        unsigned su = __float_as_uint(sv);
        unsigned ord = su ^ ((unsigned)((int)su >> 31) | 0x80000000u);
        T[r][ccol] = (unsigned short)(ord >> 16);
      }
    }
  }
  __syncthreads();

  const int srow0 = tid >> 4, scol0 = (tid & 15) * 8;
  #pragma unroll
  for (int p = 0; p < 8; ++p) {
    const int r = p * 16 + srow0;
    short8 w = *(const short8*)&T[r][scol0];
    *(short8*)&simq[(size_t)(i0 + r) * BB + j0 + scol0] = w;
  }
  if (bi != bj) {
    #pragma unroll
    for (int p = 0; p < 8; ++p) {
      const int col = p * 16 + srow0;
      unsigned short tmp[8];
      #pragma unroll
      for (int t = 0; t < 8; ++t) tmp[t] = T[scol0 + t][col];
      *(short8*)&simq[(size_t)(j0 + col) * BB + i0 + scol0] = *(short8*)tmp;
    }
  }
}

// ---------------- K2: rank processing, TWO waves per row ----------------
// Block = 128 thd = 2 waves = 1 row (4096 blocks, 8192 waves). Wave h owns
// elements el=0..31/lane: global e = 32h+el, j = 512*(4h+(el>>3)) + 8*lane
// + (el&7). k[32] -> ~70 VGPR (vs 124), scans halve. Cross-wave combine via
// pop-indexed LDS slots (never reused -> ONE barrier/pop, no WAR). ks/fpn/g
// are block-uniform -> barrier counts cannot diverge.
#define TOP2UPD(k, a, b) {                                                     \
  unsigned _mx = ((k) > (a)) ? (k) : (a);                                      \
  unsigned _mn = ((k) > (a)) ? (a) : (k);                                      \
  (a) = _mx;                                                                   \
  (b) = (_mn > (b)) ? _mn : (b); }

__global__ __launch_bounds__(128) void rowproc9(const unsigned short* __restrict__ simq,
                                                const int* __restrict__ labels,
                                                float* __restrict__ partials) {
  __shared__ unsigned sred[2 * KTOP + 2][2];
  __shared__ int sint[2 + 2 * KTOP];          // spos[2] | scnt[2][KTOP]

  const int tid = threadIdx.x;
  const int lane = tid & 63;
  const int h = tid >> 6;                     // wave 0/1
  const int row = blockIdx.x;

  // ---- load this wave's half-row (4 x uint4 per lane) ----
  const uint4* rp = (const uint4*)(simq + (size_t)row * BB);
  uint4 w0 = rp[lane + (4 * h + 0) * 64];
  uint4 w1 = rp[lane + (4 * h + 1) * 64];
  uint4 w2 = rp[lane + (4 * h + 2) * 64];
  uint4 w3 = rp[lane + (4 * h + 3) * 64];

  const int myl = labels[row];
  const unsigned mh = (unsigned)(g_cmask[myl * 64 + lane] >> (32 * h));
  const unsigned lbase2 = (unsigned)((4095 - 8 * lane) << 1);

  // ---- build 32 keys ----
  unsigned k[32];
  #pragma unroll
  for (int s = 0; s < 4; ++s) {
    const uint4 w = s == 0 ? w0 : s == 1 ? w1 : s == 2 ? w2 : w3;
    const unsigned base_s = lbase2 - (unsigned)(1024 * (4 * h + s));
    #pragma unroll
    for (int q = 0; q < 4; ++q) {
      const unsigned wv = u4c(w, q);
      const int e0 = s * 8 + q * 2;
      k[e0]     = ((wv & 0xffffu) << 13)
                | (base_s - (unsigned)((q * 2) << 1)     + ((mh >> e0) & 1u));
      k[e0 + 1] = ((wv >> 16) << 13)
                | (base_s - (unsigned)((q * 2 + 1) << 1) + ((mh >> (e0 + 1)) & 1u));
    }
  }

  // ---- pos (block sum) ----
  {
    int p = wavesum_dpp(__popc(mh));
    sint[h] = p;                              // all lanes write same value
  }
  __syncthreads();
  const int pos = sint[0] + sint[1];
  const int ks = min(pos, KTOP);

  unsigned h1 = 0, h2 = 0;
  #pragma unroll
  for (int e = 0; e < 32; ++e) TOP2UPD(k[e], h1, h2);

  // ---- top-ks pops: wave max -> slot -> barrier -> block max ----
  unsigned kth = 0;
  float fp = 0.f; int fpn = 0;
  #pragma unroll
  for (int t = 0; t < KTOP; ++t) {
    if (t < ks) {
      sred[t][h] = wavemax32_dpp(h1);
    }
    __syncthreads();
    if (t < ks) {
      const unsigned g = max(sred[t][0], sred[t][1]);
      if (!(g & 1u)) { fp += ord16val(g >> 13) * (1.f / log2f((float)(t + 2)) + 1.f); fpn++; }
      if (t == ks - 1) kth = g;
      if (h1 == g) {                          // unique owner thread
        h1 = h2; h2 = ~0u;
        if (h1 == ~0u) {
          h1 = 0; h2 = 0;
          #pragma unroll
          for (int e = 0; e < 32; ++e) {
            if (k[e] < g) TOP2UPD(k[e], h1, h2);
          }
        }
      }
    }
  }

  // ---- fn: same-class keys below kth ----
  float fn = 0.f;
  if (fpn > 0) {
    unsigned f1 = 0, f2 = 0;
    #pragma unroll
    for (int e = 0; e < 32; ++e) {
      if ((k[e] & 1u) && k[e] < kth) TOP2UPD(k[e], f1, f2);
    }
    unsigned ck[KTOP];
    int nc = 0;
    #pragma unroll
    for (int u = 0; u < KTOP; ++u) {
      ck[u] = ~0u;
      if (u < fpn) {
        sred[KTOP + 1 + u][h] = wavemax32_dpp(f1);
      }
      __syncthreads();
      if (u < fpn) {
        const unsigned g = max(sred[KTOP + 1 + u][0], sred[KTOP + 1 + u][1]);
        if (g != 0u) {
          ck[u] = g; nc = u + 1;
          if (f1 == g) {
            f1 = f2; f2 = ~0u;
            if (f1 == ~0u) {
              f1 = 0; f2 = 0;
              #pragma unroll
              for (int e = 0; e < 32; ++e) {
                if ((k[e] & 1u) && k[e] < g) TOP2UPD(k[e], f1, f2);
              }
            }
          }
        }
      }
    }
    if (nc > 0) {
      int cnt[KTOP];
      #pragma unroll
      for (int u = 0; u < KTOP; ++u) cnt[u] = 0;
      #pragma unroll
      for (int e = 0; e < 32; ++e) {
        #pragma unroll
        for (int u = 0; u < KTOP; ++u) cnt[u] += (k[e] > ck[u]) ? 1 : 0;
      }
      #pragma unroll
      for (int u = 0; u < KTOP; ++u) {
        sint[2 + h * KTOP + u] = wavesum_dpp(cnt[u]);
      }
    }
    __syncthreads();
    if (nc > 0) {
      #pragma unroll
      for (int u = 0; u < KTOP; ++u) {
        if (u < nc) {
          const int rank = 1 + sint[2 + u] + sint[2 + KTOP + u];
          fn += ord16val(ck[u] >> 13) * (1.f / log2f((float)(rank + 1)) + 1.f);
        }
      }
    }
  }

  if (tid == 0) partials[row] = fp - fn;
}

// ---------------- K3: deterministic final reduction ----------------
__global__ __launch_bounds__(256) void finalreduce(const float* __restrict__ partials,
                                                   float* __restrict__ out) {
  __shared__ float s[256];
  const int tid = threadIdx.x;
  float acc = 0.f;
  for (int j = tid; j < BB; j += 256) acc += partials[j];
  s[tid] = acc; __syncthreads();
  #pragma unroll
  for (int st = 128; st; st >>= 1) { if (tid < st) s[tid] += s[tid + st]; __syncthreads(); }
  if (tid == 0) out[0] = s[0];
}

extern "C" void kernel_launch(void* const* d_in, const int* in_sizes, int n_in,
                              void* d_out, int out_size, void* d_ws, size_t ws_size,
                              hipStream_t stream) {
  const float* R      = (const float*)d_in[0];
  const int*   labels = (const int*)d_in[1];
  float* out = (float*)d_out;

  unsigned short* simq = (unsigned short*)d_ws;                          // 32 MB
  float* sq            = (float*)((char*)d_ws + (size_t)BB * BB * 2);    // 16 KB
  float* partials      = sq + BB;                                        // 16 KB

  splitsq<<<BB, 64, 0, stream>>>(R, sq);
  buildmask<<<64, 64, 0, stream>>>(labels);
  simgemm_rs2<<<NTRI, 256, 0, stream>>>(labels, sq, simq);
  rowproc9<<<BB, 128, 0, stream>>>(simq, labels, partials);
  finalreduce<<<1, 256, 0, stream>>>(partials, out);
}

// Round 23
// 89.079 us; speedup vs baseline: 1.3246x; 1.0447x over previous
//
#include <hip/hip_runtime.h>
#include <math.h>

#define BB 4096        // batch size
#define DD 512         // repr dim
#define KTOP 9         // K+1
#define MARGIN_F 0.2f
#define NT 32          // 4096/128
#define NTRI (NT * (NT + 1) / 2)   // 528 upper-triangle 128x128 blocks

typedef __attribute__((ext_vector_type(8))) short short8;
typedef __attribute__((ext_vector_type(4))) float f32x4;
typedef unsigned long long u64;

__device__ unsigned short g_Rhi[(size_t)BB * DD];
__device__ unsigned short g_Rpk[(size_t)BB * DD];   // panel-major MFMA-fragment layout
__device__ u64 g_cmask[64 * 64];   // [class][lane] bit e -> label[j(lane,e)]==class

// ---- bf16 helper (RNE) ----
__device__ __forceinline__ unsigned short f2bf(float x) {
  unsigned u = __float_as_uint(x);
  u += 0x7fffu + ((u >> 16) & 1u);
  return (unsigned short)(u >> 16);
}

// ---- 16-bit ord: monotone map of f32, truncated; dequant mid-bucket ----
__device__ __forceinline__ float ord16val(unsigned o16) {
  unsigned e = (o16 << 16) | 0x8000u;
  unsigned s = (e & 0x80000000u) ? (e ^ 0x80000000u) : ~e;
  return __uint_as_float(s);
}

// ---- DPP wave reductions ----
__device__ __forceinline__ unsigned wavemax32_dpp(unsigned c) {
#define MSTEP(CTRL, RM)                                                        \
  {                                                                            \
    unsigned o = (unsigned)__builtin_amdgcn_update_dpp(0, (int)c, CTRL, RM, 0xf, false); \
    if (o > c) c = o;                                                          \
  }
  MSTEP(0xB1, 0xf) MSTEP(0x4E, 0xf) MSTEP(0x141, 0xf) MSTEP(0x140, 0xf)
  MSTEP(0x142, 0xa) MSTEP(0x143, 0xc)
#undef MSTEP
  return (unsigned)__builtin_amdgcn_readlane((int)c, 63);
}

__device__ __forceinline__ int wavesum_dpp(int c) {
#define SSTEP(CTRL, RM)                                                        \
  c += __builtin_amdgcn_update_dpp(0, c, CTRL, RM, 0xf, false);
  SSTEP(0xB1, 0xf) SSTEP(0x4E, 0xf) SSTEP(0x141, 0xf) SSTEP(0x140, 0xf)
  SSTEP(0x142, 0xa) SSTEP(0x143, 0xc)
#undef SSTEP
  return __builtin_amdgcn_readlane(c, 63);
}

__device__ __forceinline__ unsigned u4c(const uint4& f, int q) {
  return q == 0 ? f.x : q == 1 ? f.y : q == 2 ? f.z : f.w;
}

// ---------------- K0: split R -> bf16 hi + row sqnorms ----------------
__global__ __launch_bounds__(64) void splitsq(const float* __restrict__ R,
                                              float* __restrict__ sq) {
  const int row = blockIdx.x, lane = threadIdx.x;
  const float4* r4 = (const float4*)(R + (size_t)row * DD);
  float4 a = r4[lane], b = r4[lane + 64];
  float xs[8] = {a.x, a.y, a.z, a.w, b.x, b.y, b.z, b.w};
  unsigned short hs[8];
  float s = 0.f;
  #pragma unroll
  for (int q = 0; q < 8; ++q) {
    float x = xs[q];
    s += x * x;
    hs[q] = f2bf(x);
  }
  const size_t base = (size_t)row * DD;
  *(ushort4*)&g_Rhi[base + lane * 4]       = *(ushort4*)&hs[0];
  *(ushort4*)&g_Rhi[base + 256 + lane * 4] = *(ushort4*)&hs[4];
  #pragma unroll
  for (int off = 32; off; off >>= 1) s += __shfl_down(s, off);
  if (lane == 0) sq[row] = s;
}

// ---------------- K0a: repack hi into panel-major MFMA fragment layout ----------------
// Panel p = rows p*16..p*16+15. Item idx (0..1023 per panel): ks = idx>>6,
// l = idx&63 -> 8 u16 from row p*16+(l&15), k = ks*32+(l>>4)*8.
// A wave's frag load becomes pk + panel*8192 + ks*512 + lane*8: 1KB coalesced.
__global__ __launch_bounds__(256) void repack(void) {
  const int p = blockIdx.x;
  #pragma unroll
  for (int i = 0; i < 4; ++i) {
    const int idx = i * 256 + threadIdx.x;
    const int ks = idx >> 6, l = idx & 63;
    const int row = p * 16 + (l & 15);
    const int k0 = ks * 32 + (l >> 4) * 8;
    *(uint4*)&g_Rpk[(size_t)p * 8192 + (size_t)idx * 8] =
        *(const uint4*)&g_Rhi[(size_t)row * DD + k0];
  }
}

// ---------------- K0b: per-class match bitmasks ----------------
// bit e of g_cmask[c][lane] <-> j = 512*(e>>3) + 8*lane + (e&7)  (u16-row layout)
__global__ __launch_bounds__(64) void buildmask(const int* __restrict__ labels) {
  __shared__ int slab[BB];
  const int c = blockIdx.x, lane = threadIdx.x;
  for (int i = lane; i < BB / 4; i += 64) ((int4*)slab)[i] = ((const int4*)labels)[i];
  __syncthreads();
  u64 m = 0;
  #pragma unroll
  for (int e = 0; e < 64; ++e) {
    int j = 512 * (e >> 3) + 8 * lane + (e & 7);
    m |= (u64)(slab[j] == c) << e;
  }
  g_cmask[c * 64 + lane] = m;
}

// ---------------- K1: panel-packed BARRIER-FREE MFMA GEMM ----------------
// R14's reg-direct failed on scattered gathers; panel-major layout makes every
// fragment load one coalesced 1KB wave access, sequential in ks. K-loop has
// ZERO LDS ops and ZERO barriers: 8 loads + 16 MFMA per step, reg dbuf,
// compiler vmcnt pipelines. LDS used only by the epilogue.
__global__ __launch_bounds__(256, 2) void simgemm_pk(const int* __restrict__ labels,
                                                     const float* __restrict__ sq,
                                                     unsigned short* __restrict__ simq) {
  const int x = blockIdx.x & 7;      // XCD (round-robin dispatch)
  int c = blockIdx.x >> 3;           // 0..65 within XCD
  int bi = 0, bj = 0;
  #pragma unroll
  for (int q = 0; q < 4; ++q) {
    const int bjq = (q < 2) ? (2 * x + q) : (28 - 2 * x + q);   // {2x,2x+1,30-2x,31-2x}
    const int n = bjq + 1;
    if (c >= 0 && c < n) { bj = bjq; bi = c; }
    c -= n;
  }
  const int i0 = bi * 128, j0 = bj * 128;

  __shared__ __align__(16) unsigned char smembytes[35840];   // epilogue only

  const int tid = threadIdx.x;
  const int wid = tid >> 6, lane = tid & 63;
  const int wr = wid >> 1, wc = wid & 1;
  const int lrow = lane & 15, kblk = lane >> 4;

  // fragment base pointers: panel-major, + ks*512 u16 per step
  const unsigned short* pA[4];
  const unsigned short* pB[4];
  #pragma unroll
  for (int m = 0; m < 4; ++m) {
    pA[m] = g_Rpk + (size_t)(bi * 8 + wr * 4 + m) * 8192 + lane * 8;
    pB[m] = g_Rpk + (size_t)(bj * 8 + wc * 4 + m) * 8192 + lane * 8;
  }

  f32x4 acc[4][4] = {};
  short8 fa[2][4], fb[2][4];

  #pragma unroll
  for (int m = 0; m < 4; ++m) {
    fa[0][m] = *(const short8*)(pA[m]);
    fb[0][m] = *(const short8*)(pB[m]);
  }

  #pragma unroll
  for (int step = 0; step < 16; ++step) {
    const int cur = step & 1;
    if (step < 15) {
      const int koff = (step + 1) * 512;
      #pragma unroll
      for (int m = 0; m < 4; ++m) {
        fa[cur ^ 1][m] = *(const short8*)(pA[m] + koff);
        fb[cur ^ 1][m] = *(const short8*)(pB[m] + koff);
      }
    }
    #pragma unroll
    for (int m = 0; m < 4; ++m) {
      #pragma unroll
      for (int n = 0; n < 4; ++n) {
        acc[m][n] = __builtin_amdgcn_mfma_f32_16x16x32_bf16(fa[cur][m], fb[cur][n], acc[m][n], 0, 0, 0);
      }
    }
  }

  // ---- epilogue: quantize to u16 ord into LDS T[128][132], coalesced dual store ----
  unsigned short (*T)[132] = (unsigned short (*)[132])smembytes;   // 33792 B
  float* sqi = (float*)(smembytes + 33792);
  float* sqj = (float*)(smembytes + 34304);
  int* labi  = (int*)(smembytes + 34816);
  int* labj  = (int*)(smembytes + 35328);
  if (tid < 128) { sqi[tid] = sq[i0 + tid]; labi[tid] = labels[i0 + tid]; }
  else { int t2 = tid - 128; sqj[t2] = sq[j0 + t2]; labj[t2] = labels[j0 + t2]; }
  __syncthreads();

  #pragma unroll
  for (int m = 0; m < 4; ++m) {
    const int rbase = wr * 64 + m * 16 + kblk * 4;
    #pragma unroll
    for (int n = 0; n < 4; ++n) {
      const int ccol = wc * 64 + n * 16 + lrow;
      const float sqc = sqj[ccol];
      const int lc_ = labj[ccol];
      #pragma unroll
      for (int reg = 0; reg < 4; ++reg) {
        const int r = rbase + reg;
        float res = sqi[r] - 2.0f * acc[m][n][reg] + sqc;
        float dd = (res <= 0.f) ? 0.f : sqrtf(res);
        float sv = -dd + ((labi[r] != lc_) ? MARGIN_F : 0.f);
        unsigned su = __float_as_uint(sv);
        unsigned ord = su ^ ((unsigned)((int)su >> 31) | 0x80000000u);
        T[r][ccol] = (unsigned short)(ord >> 16);
      }
    }
  }
  __syncthreads();

  const int srow0 = tid >> 4, scol0 = (tid & 15) * 8;
  #pragma unroll
  for (int p = 0; p < 8; ++p) {
    const int r = p * 16 + srow0;
    short8 w = *(const short8*)&T[r][scol0];
    *(short8*)&simq[(size_t)(i0 + r) * BB + j0 + scol0] = w;
  }
  if (bi != bj) {
    #pragma unroll
    for (int p = 0; p < 8; ++p) {
      const int col = p * 16 + srow0;
      unsigned short tmp[8];
      #pragma unroll
      for (int t = 0; t < 8; ++t) tmp[t] = T[scol0 + t][col];
      *(short8*)&simq[(size_t)(j0 + col) * BB + i0 + scol0] = *(short8*)tmp;
    }
  }
}

// ---------------- K2: rank processing, TWO waves per row (R21 best-known) ----------------
#define TOP2UPD(k, a, b) {                                                     \
  unsigned _mx = ((k) > (a)) ? (k) : (a);                                      \
  unsigned _mn = ((k) > (a)) ? (a) : (k);                                      \
  (a) = _mx;                                                                   \
  (b) = (_mn > (b)) ? _mn : (b); }

__global__ __launch_bounds__(128) void rowproc9(const unsigned short* __restrict__ simq,
                                                const int* __restrict__ labels,
                                                float* __restrict__ partials) {
  __shared__ unsigned sred[2 * KTOP + 2][2];
  __shared__ int sint[2 + 2 * KTOP];          // spos[2] | scnt[2][KTOP]

  const int tid = threadIdx.x;
  const int lane = tid & 63;
  const int h = tid >> 6;                     // wave 0/1
  const int row = blockIdx.x;

  const uint4* rp = (const uint4*)(simq + (size_t)row * BB);
  uint4 w0 = rp[lane + (4 * h + 0) * 64];
  uint4 w1 = rp[lane + (4 * h + 1) * 64];
  uint4 w2 = rp[lane + (4 * h + 2) * 64];
  uint4 w3 = rp[lane + (4 * h + 3) * 64];

  const int myl = labels[row];
  const unsigned mh = (unsigned)(g_cmask[myl * 64 + lane] >> (32 * h));
  const unsigned lbase2 = (unsigned)((4095 - 8 * lane) << 1);

  unsigned k[32];
  #pragma unroll
  for (int s = 0; s < 4; ++s) {
    const uint4 w = s == 0 ? w0 : s == 1 ? w1 : s == 2 ? w2 : w3;
    const unsigned base_s = lbase2 - (unsigned)(1024 * (4 * h + s));
    #pragma unroll
    for (int q = 0; q < 4; ++q) {
      const unsigned wv = u4c(w, q);
      const int e0 = s * 8 + q * 2;
      k[e0]     = ((wv & 0xffffu) << 13)
                | (base_s - (unsigned)((q * 2) << 1)     + ((mh >> e0) & 1u));
      k[e0 + 1] = ((wv >> 16) << 13)
                | (base_s - (unsigned)((q * 2 + 1) << 1) + ((mh >> (e0 + 1)) & 1u));
    }
  }

  {
    int p = wavesum_dpp(__popc(mh));
    sint[h] = p;
  }
  __syncthreads();
  const int pos = sint[0] + sint[1];
  const int ks = min(pos, KTOP);

  unsigned h1 = 0, h2 = 0;
  #pragma unroll
  for (int e = 0; e < 32; ++e) TOP2UPD(k[e], h1, h2);

  unsigned kth = 0;
  float fp = 0.f; int fpn = 0;
  #pragma unroll
  for (int t = 0; t < KTOP; ++t) {
    if (t < ks) {
      sred[t][h] = wavemax32_dpp(h1);
    }
    __syncthreads();
    if (t < ks) {
      const unsigned g = max(sred[t][0], sred[t][1]);
      if (!(g & 1u)) { fp += ord16val(g >> 13) * (1.f / log2f((float)(t + 2)) + 1.f); fpn++; }
      if (t == ks - 1) kth = g;
      if (h1 == g) {
        h1 = h2; h2 = ~0u;
        if (h1 == ~0u) {
          h1 = 0; h2 = 0;
          #pragma unroll
          for (int e = 0; e < 32; ++e) {
            if (k[e] < g) TOP2UPD(k[e], h1, h2);
          }
        }
      }
    }
  }

  float fn = 0.f;
  if (fpn > 0) {
    unsigned f1 = 0, f2 = 0;
    #pragma unroll
    for (int e = 0; e < 32; ++e) {
      if ((k[e] & 1u) && k[e] < kth) TOP2UPD(k[e], f1, f2);
    }
    unsigned ck[KTOP];
    int nc = 0;
    #pragma unroll
    for (int u = 0; u < KTOP; ++u) {
      ck[u] = ~0u;
      if (u < fpn) {
        sred[KTOP + 1 + u][h] = wavemax32_dpp(f1);
      }
      __syncthreads();
      if (u < fpn) {
        const unsigned g = max(sred[KTOP + 1 + u][0], sred[KTOP + 1 + u][1]);
        if (g != 0u) {
          ck[u] = g; nc = u + 1;
          if (f1 == g) {
            f1 = f2; f2 = ~0u;
            if (f1 == ~0u) {
              f1 = 0; f2 = 0;
              #pragma unroll
              for (int e = 0; e < 32; ++e) {
                if ((k[e] & 1u) && k[e] < g) TOP2UPD(k[e], f1, f2);
              }
            }
          }
        }
      }
    }
    if (nc > 0) {
      int cnt[KTOP];
      #pragma unroll
      for (int u = 0; u < KTOP; ++u) cnt[u] = 0;
      #pragma unroll
      for (int e = 0; e < 32; ++e) {
        #pragma unroll
        for (int u = 0; u < KTOP; ++u) cnt[u] += (k[e] > ck[u]) ? 1 : 0;
      }
      #pragma unroll
      for (int u = 0; u < KTOP; ++u) {
        sint[2 + h * KTOP + u] = wavesum_dpp(cnt[u]);
      }
    }
    __syncthreads();
    if (nc > 0) {
      #pragma unroll
      for (int u = 0; u < KTOP; ++u) {
        if (u < nc) {
          const int rank = 1 + sint[2 + u] + sint[2 + KTOP + u];
          fn += ord16val(ck[u] >> 13) * (1.f / log2f((float)(rank + 1)) + 1.f);
        }
      }
    }
  }

  if (tid == 0) partials[row] = fp - fn;
}

// ---------------- K3: deterministic final reduction ----------------
__global__ __launch_bounds__(256) void finalreduce(const float* __restrict__ partials,
                                                   float* __restrict__ out) {
  __shared__ float s[256];
  const int tid = threadIdx.x;
  float acc = 0.f;
  for (int j = tid; j < BB; j += 256) acc += partials[j];
  s[tid] = acc; __syncthreads();
  #pragma unroll
  for (int st = 128; st; st >>= 1) { if (tid < st) s[tid] += s[tid + st]; __syncthreads(); }
  if (tid == 0) out[0] = s[0];
}

extern "C" void kernel_launch(void* const* d_in, const int* in_sizes, int n_in,
                              void* d_out, int out_size, void* d_ws, size_t ws_size,
                              hipStream_t stream) {
  const float* R      = (const float*)d_in[0];
  const int*   labels = (const int*)d_in[1];
  float* out = (float*)d_out;

  unsigned short* simq = (unsigned short*)d_ws;                          // 32 MB
  float* sq            = (float*)((char*)d_ws + (size_t)BB * BB * 2);    // 16 KB
  float* partials      = sq + BB;                                        // 16 KB

  splitsq<<<BB, 64, 0, stream>>>(R, sq);
  repack<<<BB / 16, 256, 0, stream>>>();
  buildmask<<<64, 64, 0, stream>>>(labels);
  simgemm_pk<<<NTRI, 256, 0, stream>>>(labels, sq, simq);
  rowproc9<<<BB, 128, 0, stream>>>(simq, labels, partials);
  finalreduce<<<1, 256, 0, stream>>>(partials, out);
}